// Round 1
// baseline (175.672 us; speedup 1.0000x reference)
//
#include <hip/hip_runtime.h>
#include <hip/hip_bf16.h>
#include <math.h>

typedef __bf16 bf16x8 __attribute__((ext_vector_type(8)));
typedef float  f32x4  __attribute__((ext_vector_type(4)));

#define COL_SLICES 8

// ---------------- normalize + bf16 cast ----------------
__global__ void normalize_kernel(const float* __restrict__ tab,
                                 const float* __restrict__ ts,
                                 __hip_bfloat16* __restrict__ zn,
                                 int N, int E) {
    const int row = blockIdx.x;  // [0, 2N)
    const float* src = row < N ? tab + (size_t)row * E : ts + (size_t)(row - N) * E;
    const int tid = threadIdx.x;
    float ss = 0.f;
    for (int j = tid; j < E; j += blockDim.x) {
        float v = src[j];
        ss += v * v;
    }
    for (int m = 32; m >= 1; m >>= 1) ss += __shfl_xor(ss, m);
    __shared__ float wsum[8];
    const int wave = tid >> 6, lane = tid & 63;
    if (lane == 0) wsum[wave] = ss;
    __syncthreads();
    const int nw = blockDim.x >> 6;
    float tot = 0.f;
    for (int w = 0; w < nw; ++w) tot += wsum[w];
    const float inv = 1.0f / fmaxf(sqrtf(tot), 1e-8f);
    for (int j = tid; j < E; j += blockDim.x)
        zn[(size_t)row * E + j] = __float2bfloat16(src[j] * inv);
}

// ---------------- label histogram ----------------
__global__ void hist_kernel(const int* __restrict__ labels, int* __restrict__ cnt, int N) {
    int i = blockIdx.x * blockDim.x + threadIdx.x;
    if (i < N) atomicAdd(&cnt[labels[i]], 1);
}

// ---------------- fused sim GEMM + exp rowsum + positives rowsum ----------------
// Block tile: 64 rows x 64 cols, 4 waves (2x2), each wave 32x32 via 2x2 16x16x32 MFMAs.
// Grid: (2N/64) row-blocks x COL_SLICES; each block loops over its slice's col tiles.
__global__ __launch_bounds__(256) void simloss_kernel(
    const __hip_bfloat16* __restrict__ zn,
    const int* __restrict__ labels,
    float* __restrict__ rowExp, float* __restrict__ rowPos,
    int N, int E)
{
    const int twoN = 2 * N;
    const int tid  = threadIdx.x;
    const int lane = tid & 63;
    const int wave = tid >> 6;
    const int wr = wave >> 1, wc = wave & 1;
    const int l15 = lane & 15, lg = lane >> 4;

    const int rowBase = blockIdx.x * 64 + wr * 32;
    const int sliceCols = twoN / COL_SLICES;
    const int colSliceBase = blockIdx.y * sliceCols;
    const int nTiles = sliceCols / 64;

    // Hoist A fragments across all col tiles: aFrag[rf][kstep]  (E == 256 -> 8 ksteps)
    bf16x8 aFrag[2][8];
    #pragma unroll
    for (int rf = 0; rf < 2; ++rf) {
        const int rA = rowBase + rf * 16 + l15;
        const __hip_bfloat16* p = zn + (size_t)rA * E + lg * 8;
        #pragma unroll
        for (int ks = 0; ks < 8; ++ks)
            aFrag[rf][ks] = *(const bf16x8*)(p + ks * 32);
    }

    // Rows this lane owns in C/D (col = lane&15, row = (lane>>4)*4 + reg) + their labels
    int rowR[2][4]; int labR[2][4];
    #pragma unroll
    for (int rf = 0; rf < 2; ++rf)
        #pragma unroll
        for (int j = 0; j < 4; ++j) {
            const int r = rowBase + rf * 16 + lg * 4 + j;
            rowR[rf][j] = r;
            labR[rf][j] = labels[r >= N ? r - N : r];
        }

    float expPart[2][4] = {{0.f,0.f,0.f,0.f},{0.f,0.f,0.f,0.f}};
    float posPart[2][4] = {{0.f,0.f,0.f,0.f},{0.f,0.f,0.f,0.f}};

    const float EXP_SCALE = 10.0f;  // 1/T

    for (int t = 0; t < nTiles; ++t) {
        const int colBase = colSliceBase + t * 64 + wc * 32;
        int colB[2], labC[2];
        #pragma unroll
        for (int cf = 0; cf < 2; ++cf) {
            colB[cf] = colBase + cf * 16 + l15;
            labC[cf] = labels[colB[cf] >= N ? colB[cf] - N : colB[cf]];
        }

        f32x4 zero = {0.f, 0.f, 0.f, 0.f};
        f32x4 acc[2][2];
        acc[0][0] = zero; acc[0][1] = zero; acc[1][0] = zero; acc[1][1] = zero;

        const __hip_bfloat16* pb0 = zn + (size_t)colB[0] * E + lg * 8;
        const __hip_bfloat16* pb1 = zn + (size_t)colB[1] * E + lg * 8;
        #pragma unroll
        for (int ks = 0; ks < 8; ++ks) {
            bf16x8 b0 = *(const bf16x8*)(pb0 + ks * 32);
            bf16x8 b1 = *(const bf16x8*)(pb1 + ks * 32);
            acc[0][0] = __builtin_amdgcn_mfma_f32_16x16x32_bf16(aFrag[0][ks], b0, acc[0][0], 0, 0, 0);
            acc[0][1] = __builtin_amdgcn_mfma_f32_16x16x32_bf16(aFrag[0][ks], b1, acc[0][1], 0, 0, 0);
            acc[1][0] = __builtin_amdgcn_mfma_f32_16x16x32_bf16(aFrag[1][ks], b0, acc[1][0], 0, 0, 0);
            acc[1][1] = __builtin_amdgcn_mfma_f32_16x16x32_bf16(aFrag[1][ks], b1, acc[1][1], 0, 0, 0);
        }

        // fused epilogue: exp row-sum (skip diagonal) + cross-view label-matched sim row-sum
        #pragma unroll
        for (int rf = 0; rf < 2; ++rf)
            #pragma unroll
            for (int cf = 0; cf < 2; ++cf) {
                const int c = colB[cf];
                #pragma unroll
                for (int j = 0; j < 4; ++j) {
                    const float s = acc[rf][cf][j];
                    const int r = rowR[rf][j];
                    const float e = __expf(s * EXP_SCALE);
                    if (r != c) expPart[rf][j] += e;
                    const bool cross = (r < N) != (c < N);
                    if (cross && (labR[rf][j] == labC[cf])) posPart[rf][j] += s;
                }
            }
    }

    // Reduce across the 16 lanes that share each row (xor over lane bits 0..3), then atomics
    #pragma unroll
    for (int rf = 0; rf < 2; ++rf)
        #pragma unroll
        for (int j = 0; j < 4; ++j) {
            float ep = expPart[rf][j], pp = posPart[rf][j];
            for (int m = 1; m <= 8; m <<= 1) {
                ep += __shfl_xor(ep, m);
                pp += __shfl_xor(pp, m);
            }
            if (l15 == 0) {
                const int r = rowR[rf][j];
                atomicAdd(&rowExp[r], ep);
                atomicAdd(&rowPos[r], pp);
            }
        }
}

// ---------------- finalize: per-row logits sum -> scalar loss ----------------
__global__ void finalize_kernel(const float* __restrict__ rowExp,
                                const float* __restrict__ rowPos,
                                const int* __restrict__ labels,
                                const int* __restrict__ cnt,
                                float* __restrict__ out, int N) {
    const int twoN = 2 * N;
    const int tid = threadIdx.x;
    double part = 0.0;
    for (int i = tid; i < twoN; i += blockDim.x) {
        const int lab = labels[i >= N ? i - N : i];
        const double mc = 2.0 * (double)cnt[lab];
        const double g = ((double)rowPos[i] * 10.0 - (double)N * log((double)rowExp[i])) / mc;
        part += g;
    }
    for (int m = 32; m >= 1; m >>= 1) part += __shfl_xor(part, m);
    __shared__ double wsum[4];
    const int wave = tid >> 6, lane = tid & 63;
    if (lane == 0) wsum[wave] = part;
    __syncthreads();
    if (tid == 0) {
        const double tot = wsum[0] + wsum[1] + wsum[2] + wsum[3];
        out[0] = (float)(-tot / (double)twoN);
    }
}

extern "C" void kernel_launch(void* const* d_in, const int* in_sizes, int n_in,
                              void* d_out, int out_size, void* d_ws, size_t ws_size,
                              hipStream_t stream) {
    const float* tab    = (const float*)d_in[0];
    const float* ts     = (const float*)d_in[1];
    const int*   labels = (const int*)d_in[2];
    const int N = in_sizes[2];        // 4096
    const int E = in_sizes[0] / N;    // 256
    const int twoN = 2 * N;

    char* ws = (char*)d_ws;
    __hip_bfloat16* zn = (__hip_bfloat16*)ws;
    const size_t znBytes = (size_t)twoN * E * sizeof(__hip_bfloat16);
    float* rowExp = (float*)(ws + znBytes);
    float* rowPos = rowExp + twoN;
    int*   cnt    = (int*)(rowPos + twoN);

    // zero accumulators + histogram (harness poisons ws; we must re-zero every call)
    hipMemsetAsync(rowExp, 0, (size_t)(2 * twoN) * sizeof(float) + 256 * sizeof(int), stream);

    normalize_kernel<<<twoN, 256, 0, stream>>>(tab, ts, zn, N, E);
    hist_kernel<<<(N + 255) / 256, 256, 0, stream>>>(labels, cnt, N);

    dim3 grid(twoN / 64, COL_SLICES);
    simloss_kernel<<<grid, 256, 0, stream>>>(zn, labels, rowExp, rowPos, N, E);

    finalize_kernel<<<1, 256, 0, stream>>>(rowExp, rowPos, labels, cnt, (float*)d_out, N);
}

// Round 2
// 113.701 us; speedup vs baseline: 1.5450x; 1.5450x over previous
//
#include <hip/hip_runtime.h>
#include <hip/hip_bf16.h>
#include <math.h>

typedef __bf16 bf16x8 __attribute__((ext_vector_type(8)));
typedef __bf16 bf16x4 __attribute__((ext_vector_type(4)));
typedef float  f32x4  __attribute__((ext_vector_type(4)));

#define N_ROWS 4096
#define E_DIM  256
#define BM 128
#define BN 128
#define BK 64

__device__ __forceinline__ void gload_lds16(const void* g, void* l) {
    __builtin_amdgcn_global_load_lds(
        (const __attribute__((address_space(1))) void*)g,
        (__attribute__((address_space(3))) void*)l,
        16, 0, 0);
}

// ---------------- normalize + bf16 cast: one wave per row ----------------
__global__ __launch_bounds__(64) void normalize_kernel(const float* __restrict__ tab,
                                                       const float* __restrict__ ts,
                                                       __hip_bfloat16* __restrict__ zn) {
    const int row = blockIdx.x;  // [0, 2N)
    const float* src = row < N_ROWS ? tab + (size_t)row * E_DIM
                                    : ts + (size_t)(row - N_ROWS) * E_DIM;
    const int lane = threadIdx.x;
    const float4 v = *(const float4*)(src + lane * 4);
    float ss = v.x * v.x + v.y * v.y + v.z * v.z + v.w * v.w;
    #pragma unroll
    for (int m = 32; m >= 1; m >>= 1) ss += __shfl_xor(ss, m);
    const float inv = 1.0f / fmaxf(sqrtf(ss), 1e-8f);
    bf16x4 o = { (__bf16)(v.x * inv), (__bf16)(v.y * inv),
                 (__bf16)(v.z * inv), (__bf16)(v.w * inv) };
    *(bf16x4*)(zn + (size_t)row * E_DIM + lane * 4) = o;
}

// ---------------- label histogram ----------------
__global__ void hist_kernel(const int* __restrict__ labels, int* __restrict__ cnt, int N) {
    int i = blockIdx.x * blockDim.x + threadIdx.x;
    if (i < N) atomicAdd(&cnt[labels[i]], 1);
}

// ---------------- fused sim GEMM + exp rowsum + positives rowsum ----------------
// 128x128 block tile, BK=64, double-buffered LDS via global_load_lds(16B),
// XOR-swizzled 16B chunks (chunk ^ (row&7)), 4 waves as 2x2, 64x64 wave tile.
__global__ __launch_bounds__(256, 2) void simloss_kernel(
    const __hip_bfloat16* __restrict__ zn,
    const int* __restrict__ labels,
    float* __restrict__ rowExp, float* __restrict__ rowPos)
{
    __shared__ __align__(16) char lds[2][2][BM * BK * 2];  // [buf][A=0/B=1][16KB]
    __shared__ int labRow[BM];
    __shared__ int labCol[BN];

    const int tid  = threadIdx.x;
    const int lane = tid & 63;
    const int wave = tid >> 6;
    const int wr = wave >> 1, wc = wave & 1;
    const int l15 = lane & 15, lg = lane >> 4;

    const int rb = blockIdx.x * BM;
    const int cb = blockIdx.y * BN;

    if (tid < BM)      labRow[tid]      = labels[(rb + tid) & (N_ROWS - 1)];
    else               labCol[tid - BM] = labels[(cb + tid - BM) & (N_ROWS - 1)];

    // ---- staging: 16KB per matrix = 4 issues/thread of 16B; linear LDS dest,
    // ---- pre-swizzled global source (chunk ^ (row&7)) so reads can swizzle.
    auto stage = [&](int buf, int kt) {
        #pragma unroll
        for (int it = 0; it < 4; ++it) {
            const int idx = it * 256 + wave * 64 + lane;  // 16B chunk id, 0..1023
            const int row = idx >> 3;                     // 0..127
            const int sch = (idx & 7) ^ (row & 7);        // swizzled chunk within row
            const __hip_bfloat16* gA = zn + (size_t)(rb + row) * E_DIM + kt * BK + sch * 8;
            const __hip_bfloat16* gB = zn + (size_t)(cb + row) * E_DIM + kt * BK + sch * 8;
            char* lA = &lds[buf][0][(it * 256 + wave * 64) * 16];  // wave-uniform base
            char* lB = &lds[buf][1][(it * 256 + wave * 64) * 16];
            gload_lds16(gA, lA);
            gload_lds16(gB, lB);
        }
    };

    f32x4 acc[4][4];
    #pragma unroll
    for (int i = 0; i < 4; ++i)
        #pragma unroll
        for (int j = 0; j < 4; ++j) acc[i][j] = (f32x4){0.f, 0.f, 0.f, 0.f};

    stage(0, 0);
    __syncthreads();

    int cur = 0;
    #pragma unroll
    for (int kt = 0; kt < E_DIM / BK; ++kt) {
        if (kt + 1 < E_DIM / BK) stage(cur ^ 1, kt + 1);
        const char* aBase = lds[cur][0];
        const char* bBase = lds[cur][1];
        #pragma unroll
        for (int ks = 0; ks < 2; ++ks) {
            bf16x8 af[4], bfr[4];
            #pragma unroll
            for (int rf = 0; rf < 4; ++rf) {
                const int r = wr * 64 + rf * 16 + l15;
                af[rf] = *(const bf16x8*)(aBase + r * 128 + (((ks * 4 + lg) ^ (r & 7)) << 4));
            }
            #pragma unroll
            for (int cf = 0; cf < 4; ++cf) {
                const int c = wc * 64 + cf * 16 + l15;
                bfr[cf] = *(const bf16x8*)(bBase + c * 128 + (((ks * 4 + lg) ^ (c & 7)) << 4));
            }
            #pragma unroll
            for (int rf = 0; rf < 4; ++rf)
                #pragma unroll
                for (int cf = 0; cf < 4; ++cf)
                    acc[rf][cf] = __builtin_amdgcn_mfma_f32_16x16x32_bf16(af[rf], bfr[cf], acc[rf][cf], 0, 0, 0);
        }
        __syncthreads();
        cur ^= 1;
    }

    // ---- fused epilogue (once per block, acc register-resident) ----
    const bool cross   = ((rb < N_ROWS) != (cb < N_ROWS));  // block-uniform
    const bool hasDiag = (rb == cb);                        // block-uniform

    int cl[4], clab[4];
    #pragma unroll
    for (int cf = 0; cf < 4; ++cf) {
        cl[cf]   = wc * 64 + cf * 16 + l15;
        clab[cf] = labCol[cl[cf]];
    }

    #pragma unroll
    for (int rf = 0; rf < 4; ++rf) {
        #pragma unroll
        for (int j = 0; j < 4; ++j) {
            const int rloc = wr * 64 + rf * 16 + lg * 4 + j;
            const int rlab = labRow[rloc];
            float ep = 0.f, pp = 0.f;
            #pragma unroll
            for (int cf = 0; cf < 4; ++cf) {
                const float s = acc[rf][cf][j];
                float e = __expf(s * 10.0f);  // 1/T = 10
                if (hasDiag && rloc == cl[cf]) e = 0.f;
                ep += e;
                if (cross && rlab == clab[cf]) pp += s;
            }
            #pragma unroll
            for (int m = 1; m <= 8; m <<= 1) {
                ep += __shfl_xor(ep, m);
                pp += __shfl_xor(pp, m);
            }
            if (l15 == 0) {
                const int r = rb + rloc;
                atomicAdd(&rowExp[r], ep);
                if (cross) atomicAdd(&rowPos[r], pp);
            }
        }
    }
}

// ---------------- finalize: per-row logits sum -> scalar loss ----------------
__global__ void finalize_kernel(const float* __restrict__ rowExp,
                                const float* __restrict__ rowPos,
                                const int* __restrict__ labels,
                                const int* __restrict__ cnt,
                                float* __restrict__ out, int N) {
    const int twoN = 2 * N;
    const int tid = threadIdx.x;
    double part = 0.0;
    for (int i = tid; i < twoN; i += blockDim.x) {
        const int lab = labels[i >= N ? i - N : i];
        const double mc = 2.0 * (double)cnt[lab];
        const double g = ((double)rowPos[i] * 10.0 - (double)N * log((double)rowExp[i])) / mc;
        part += g;
    }
    for (int m = 32; m >= 1; m >>= 1) part += __shfl_xor(part, m);
    __shared__ double wsum[4];
    const int wave = tid >> 6, lane = tid & 63;
    if (lane == 0) wsum[wave] = part;
    __syncthreads();
    if (tid == 0) {
        const double tot = wsum[0] + wsum[1] + wsum[2] + wsum[3];
        out[0] = (float)(-tot / (double)twoN);
    }
}

extern "C" void kernel_launch(void* const* d_in, const int* in_sizes, int n_in,
                              void* d_out, int out_size, void* d_ws, size_t ws_size,
                              hipStream_t stream) {
    const float* tab    = (const float*)d_in[0];
    const float* ts     = (const float*)d_in[1];
    const int*   labels = (const int*)d_in[2];
    const int N = in_sizes[2];        // 4096
    const int twoN = 2 * N;

    char* ws = (char*)d_ws;
    __hip_bfloat16* zn = (__hip_bfloat16*)ws;
    const size_t znBytes = (size_t)twoN * E_DIM * sizeof(__hip_bfloat16);
    float* rowExp = (float*)(ws + znBytes);
    float* rowPos = rowExp + twoN;
    int*   cnt    = (int*)(rowPos + twoN);

    hipMemsetAsync(rowExp, 0, (size_t)(2 * twoN) * sizeof(float) + 256 * sizeof(int), stream);

    normalize_kernel<<<twoN, 64, 0, stream>>>(tab, ts, zn);
    hist_kernel<<<(N + 255) / 256, 256, 0, stream>>>(labels, cnt, N);

    dim3 grid(twoN / BM, twoN / BN);
    simloss_kernel<<<grid, 256, 0, stream>>>(zn, labels, rowExp, rowPos);

    finalize_kernel<<<1, 256, 0, stream>>>(rowExp, rowPos, labels, cnt, (float*)d_out, N);
}

// Round 3
// 96.730 us; speedup vs baseline: 1.8161x; 1.1755x over previous
//
#include <hip/hip_runtime.h>
#include <hip/hip_bf16.h>
#include <math.h>

typedef __bf16 bf16x8 __attribute__((ext_vector_type(8)));
typedef __bf16 bf16x4 __attribute__((ext_vector_type(4)));
typedef float  f32x4  __attribute__((ext_vector_type(4)));

#define N_ROWS 4096
#define E_DIM  256
#define BM 128
#define BN 128
#define BK 64
#define LOG2E10 14.426950408889634f  /* 10 * log2(e) */

__device__ __forceinline__ void gload_lds16(const void* g, void* l) {
    __builtin_amdgcn_global_load_lds(
        (const __attribute__((address_space(1))) void*)g,
        (__attribute__((address_space(3))) void*)l,
        16, 0, 0);
}

// ---------------- prep: normalize (1 row/wave) + zero accumulators + histogram ----------------
__global__ __launch_bounds__(256) void prep_kernel(
    const float* __restrict__ tab, const float* __restrict__ ts,
    const int* __restrict__ labels, __hip_bfloat16* __restrict__ zn,
    float* __restrict__ rowExp, float* __restrict__ rowPos, int* __restrict__ cnt)
{
    const int tid  = threadIdx.x;
    const int wave = tid >> 6, lane = tid & 63;
    const int row  = blockIdx.x * 4 + wave;

    if (tid < 4) {
        const int r = blockIdx.x * 4 + tid;
        rowExp[r] = 0.f;
        rowPos[r] = 0.f;
        if (r < N_ROWS) atomicAdd(&cnt[labels[r]], 1);
    }

    const float* src = row < N_ROWS ? tab + (size_t)row * E_DIM
                                    : ts + (size_t)(row - N_ROWS) * E_DIM;
    const float4 v = *(const float4*)(src + lane * 4);
    float ss = v.x * v.x + v.y * v.y + v.z * v.z + v.w * v.w;
    #pragma unroll
    for (int m = 32; m >= 1; m >>= 1) ss += __shfl_xor(ss, m);
    const float inv = 1.0f / fmaxf(sqrtf(ss), 1e-8f);
    bf16x4 o = { (__bf16)(v.x * inv), (__bf16)(v.y * inv),
                 (__bf16)(v.z * inv), (__bf16)(v.w * inv) };
    *(bf16x4*)(zn + (size_t)row * E_DIM + lane * 4) = o;
}

// ---------------- fused sim GEMM + exp rowsum + positives rowsum ----------------
// 128x128 tile, BK=64 SINGLE-buffered (33KB LDS -> 4 blocks/CU), global_load_lds(16B),
// XOR-swizzled 16B chunks (chunk ^ (row&7)) both sides, 4 waves 2x2, 64x64/wave.
__global__ __launch_bounds__(256, 4) void simloss_kernel(
    const __hip_bfloat16* __restrict__ zn,
    const int* __restrict__ labels,
    float* __restrict__ rowExp, float* __restrict__ rowPos)
{
    __shared__ __align__(16) char ldsA[BM * BK * 2];  // 16KB
    __shared__ __align__(16) char ldsB[BN * BK * 2];  // 16KB
    __shared__ int labRow[BM];
    __shared__ int labCol[BN];

    const int tid  = threadIdx.x;
    const int lane = tid & 63;
    const int wave = tid >> 6;
    const int wr = wave >> 1, wc = wave & 1;
    const int l15 = lane & 15, lg = lane >> 4;

    const int rb = blockIdx.x * BM;
    const int cb = blockIdx.y * BN;

    if (tid < BM)      labRow[tid]      = labels[(rb + tid) & (N_ROWS - 1)];
    else               labCol[tid - BM] = labels[(cb + tid - BM) & (N_ROWS - 1)];

    f32x4 acc[4][4];
    #pragma unroll
    for (int i = 0; i < 4; ++i)
        #pragma unroll
        for (int j = 0; j < 4; ++j) acc[i][j] = (f32x4){0.f, 0.f, 0.f, 0.f};

    #pragma unroll
    for (int kt = 0; kt < E_DIM / BK; ++kt) {
        // ---- stage: 16KB/matrix = 4 chunks/thread; linear LDS dest (wave-uniform
        // ---- base + lane*16), pre-swizzled global source chunk = (c ^ (row&7)).
        #pragma unroll
        for (int it = 0; it < 4; ++it) {
            const int idx = it * 256 + wave * 64 + lane;  // 16B chunk id 0..1023
            const int row = idx >> 3;                     // 0..127
            const int sch = (idx & 7) ^ (row & 7);
            char* lA = ldsA + (it * 256 + wave * 64) * 16;
            char* lB = ldsB + (it * 256 + wave * 64) * 16;
            gload_lds16(zn + (size_t)(rb + row) * E_DIM + kt * BK + sch * 8, lA);
            gload_lds16(zn + (size_t)(cb + row) * E_DIM + kt * BK + sch * 8, lB);
        }
        __syncthreads();  // drains vmcnt(0): staged data visible

        #pragma unroll
        for (int ks = 0; ks < 2; ++ks) {
            bf16x8 af[4], bfr[4];
            #pragma unroll
            for (int rf = 0; rf < 4; ++rf) {
                const int r = wr * 64 + rf * 16 + l15;
                af[rf] = *(const bf16x8*)(ldsA + r * 128 + (((ks * 4 + lg) ^ (r & 7)) << 4));
            }
            #pragma unroll
            for (int cf = 0; cf < 4; ++cf) {
                const int c = wc * 64 + cf * 16 + l15;
                bfr[cf] = *(const bf16x8*)(ldsB + c * 128 + (((ks * 4 + lg) ^ (c & 7)) << 4));
            }
            #pragma unroll
            for (int rf = 0; rf < 4; ++rf)
                #pragma unroll
                for (int cf = 0; cf < 4; ++cf)
                    acc[rf][cf] = __builtin_amdgcn_mfma_f32_16x16x32_bf16(af[rf], bfr[cf], acc[rf][cf], 0, 0, 0);
        }
        __syncthreads();  // protect LDS reuse by next stage
    }

    // ---- fused epilogue, block-uniform specialization ----
    const bool cross   = ((rb < N_ROWS) != (cb < N_ROWS));
    const bool hasDiag = (rb == cb);

    int cl[4], clab[4];
    #pragma unroll
    for (int cf = 0; cf < 4; ++cf) {
        cl[cf]   = wc * 64 + cf * 16 + l15;
        clab[cf] = labCol[cl[cf]];
    }

    if (cross) {
        #pragma unroll
        for (int rf = 0; rf < 4; ++rf) {
            #pragma unroll
            for (int j = 0; j < 4; ++j) {
                const int rloc = wr * 64 + rf * 16 + lg * 4 + j;
                const int rlab = labRow[rloc];
                float ep = 0.f, pp = 0.f;
                #pragma unroll
                for (int cf = 0; cf < 4; ++cf) {
                    const float s = acc[rf][cf][j];
                    ep += __builtin_amdgcn_exp2f(s * LOG2E10);
                    if (rlab == clab[cf]) pp += s;
                }
                #pragma unroll
                for (int m = 1; m <= 8; m <<= 1) {
                    ep += __shfl_xor(ep, m);
                    pp += __shfl_xor(pp, m);
                }
                if (l15 == 0) {
                    atomicAdd(&rowExp[rb + rloc], ep);
                    atomicAdd(&rowPos[rb + rloc], pp);
                }
            }
        }
    } else if (hasDiag) {
        #pragma unroll
        for (int rf = 0; rf < 4; ++rf) {
            #pragma unroll
            for (int j = 0; j < 4; ++j) {
                const int rloc = wr * 64 + rf * 16 + lg * 4 + j;
                float ep = 0.f;
                #pragma unroll
                for (int cf = 0; cf < 4; ++cf) {
                    const float s = acc[rf][cf][j];
                    float e = __builtin_amdgcn_exp2f(s * LOG2E10);
                    if (rloc == cl[cf]) e = 0.f;
                    ep += e;
                }
                #pragma unroll
                for (int m = 1; m <= 8; m <<= 1) ep += __shfl_xor(ep, m);
                if (l15 == 0) atomicAdd(&rowExp[rb + rloc], ep);
            }
        }
    } else {
        #pragma unroll
        for (int rf = 0; rf < 4; ++rf) {
            #pragma unroll
            for (int j = 0; j < 4; ++j) {
                const int rloc = wr * 64 + rf * 16 + lg * 4 + j;
                float ep = 0.f;
                #pragma unroll
                for (int cf = 0; cf < 4; ++cf)
                    ep += __builtin_amdgcn_exp2f(acc[rf][cf][j] * LOG2E10);
                #pragma unroll
                for (int m = 1; m <= 8; m <<= 1) ep += __shfl_xor(ep, m);
                if (l15 == 0) atomicAdd(&rowExp[rb + rloc], ep);
            }
        }
    }
}

// ---------------- finalize: per-row logits sum -> scalar loss ----------------
__global__ void finalize_kernel(const float* __restrict__ rowExp,
                                const float* __restrict__ rowPos,
                                const int* __restrict__ labels,
                                const int* __restrict__ cnt,
                                float* __restrict__ out, int N) {
    const int twoN = 2 * N;
    const int tid = threadIdx.x;
    double part = 0.0;
    for (int i = tid; i < twoN; i += blockDim.x) {
        const int lab = labels[i >= N ? i - N : i];
        const double mc = 2.0 * (double)cnt[lab];
        const double g = ((double)rowPos[i] * 10.0 - (double)N * log((double)rowExp[i])) / mc;
        part += g;
    }
    for (int m = 32; m >= 1; m >>= 1) part += __shfl_xor(part, m);
    __shared__ double wsum[4];
    const int wave = tid >> 6, lane = tid & 63;
    if (lane == 0) wsum[wave] = part;
    __syncthreads();
    if (tid == 0) {
        const double tot = wsum[0] + wsum[1] + wsum[2] + wsum[3];
        out[0] = (float)(-tot / (double)twoN);
    }
}

extern "C" void kernel_launch(void* const* d_in, const int* in_sizes, int n_in,
                              void* d_out, int out_size, void* d_ws, size_t ws_size,
                              hipStream_t stream) {
    const float* tab    = (const float*)d_in[0];
    const float* ts     = (const float*)d_in[1];
    const int*   labels = (const int*)d_in[2];
    const int N = in_sizes[2];        // 4096
    const int twoN = 2 * N;

    char* ws = (char*)d_ws;
    __hip_bfloat16* zn = (__hip_bfloat16*)ws;
    const size_t znBytes = (size_t)twoN * E_DIM * sizeof(__hip_bfloat16);
    float* rowExp = (float*)(ws + znBytes);
    float* rowPos = rowExp + twoN;
    int*   cnt    = (int*)(rowPos + twoN);

    hipMemsetAsync(cnt, 0, 256 * sizeof(int), stream);

    prep_kernel<<<twoN / 4, 256, 0, stream>>>(tab, ts, labels, zn, rowExp, rowPos, cnt);

    dim3 grid(twoN / BM, twoN / BN);
    simloss_kernel<<<grid, 256, 0, stream>>>(zn, labels, rowExp, rowPos);

    finalize_kernel<<<1, 256, 0, stream>>>(rowExp, rowPos, labels, cnt, (float*)d_out, N);
}